// Round 1
// baseline (153.196 us; speedup 1.0000x reference)
//
#include <hip/hip_runtime.h>
#include <hip/hip_bf16.h>

#define C_IN    64
#define C_OUT   128
#define HH      112
#define WW      112
#define NB      16
#define KTOT    576      // C_IN * 9
#define TY      8
#define TX      16
#define HALO_Y  10
#define HALO_X  18
#define NSTEPS  36       // KTOT / 16
#define TILES_X 7
#define TILES_Y 14
#define HALO_N  (HALO_Y*HALO_X*C_IN)   // 11520 bf16 elems = 23040 B

typedef __bf16 bf16x8 __attribute__((ext_vector_type(8)));
typedef float  f32x16 __attribute__((ext_vector_type(16)));

static __device__ __forceinline__ unsigned short f2bf(float v) {
    unsigned int u = __builtin_bit_cast(unsigned int, v);
    u = u + 0x7fffu + ((u >> 16) & 1u);   // RNE
    return (unsigned short)(u >> 16);
}

// Pack spW = weight*mask into bf16 MFMA A-fragments, K reordered to (i,j,c).
// Layout: pw_frag[t][mt][lane] = 16 bytes (8 bf16), t=K-step (0..35), mt=M-tile (0..3).
// k_log(t, g=lane>>5, e) = t*16 + g*8 + e ;  ij = k_log>>6, c = k_log&63 ; k_orig = c*9 + ij
__global__ __launch_bounds__(256) void pack_w_kernel(
        const float* __restrict__ weight, const float* __restrict__ mask,
        unsigned short* __restrict__ pw) {
    int t  = blockIdx.x;           // 0..35
    int mt = threadIdx.x >> 6;     // 0..3
    int l  = threadIdx.x & 63;
    int g  = l >> 5;
    int m  = mt * 32 + (l & 31);
    unsigned int words[4];
    #pragma unroll
    for (int ew = 0; ew < 4; ++ew) {
        unsigned int w2[2];
        #pragma unroll
        for (int h = 0; h < 2; ++h) {
            int e    = ew * 2 + h;
            int klog = t * 16 + g * 8 + e;
            int ij   = klog >> 6;
            int c    = klog & 63;
            int ko   = c * 9 + ij;
            w2[h] = f2bf(weight[m * KTOT + ko] * mask[m * KTOT + ko]);
        }
        words[ew] = w2[0] | (w2[1] << 16);
    }
    uint4 o4; o4.x = words[0]; o4.y = words[1]; o4.z = words[2]; o4.w = words[3];
    ((uint4*)pw)[(t * 4 + mt) * 64 + l] = o4;
}

// Implicit-GEMM conv. Block = one batch b, one 8x16 spatial tile, all 128 c_out.
// 4 waves: wave (wm,wn): M-half wm (2 M-tiles of 32), N-half wn (2 N-tiles of 32 pixels).
__global__ __launch_bounds__(256) void sparse_conv_kernel(
        const float* __restrict__ x, const unsigned short* __restrict__ pw,
        const float* __restrict__ bias, float* __restrict__ out) {
    __shared__ __align__(16) unsigned short xs[HALO_N];

    const int bid = blockIdx.x;
    const int b   = bid / (TILES_X * TILES_Y);
    const int t98 = bid % (TILES_X * TILES_Y);
    const int tyi = t98 / TILES_X;
    const int txi = t98 % TILES_X;
    const int h0  = tyi * TY, w0 = txi * TX;
    const int tid = threadIdx.x;

    // ---- stage halo tile (fp32 -> bf16), LDS layout [yy][xx][c] with XOR swizzle ----
    const float* xb = x + (size_t)b * C_IN * HH * WW;
    #pragma unroll 1
    for (int idx = tid; idx < HALO_N; idx += 256) {
        int c   = idx / (HALO_Y * HALO_X);
        int rem = idx - c * (HALO_Y * HALO_X);
        int yy  = rem / HALO_X;
        int xx  = rem - yy * HALO_X;
        int gh  = h0 + yy - 1, gw = w0 + xx - 1;
        float v = 0.0f;
        if ((unsigned)gh < (unsigned)HH && (unsigned)gw < (unsigned)WW)
            v = xb[(c * HH + gh) * WW + gw];
        unsigned int boff = (unsigned int)(((yy * HALO_X + xx) * C_IN + c) * 2);
        boff ^= (unsigned int)((xx & 7) << 4);
        *(unsigned short*)((char*)xs + boff) = f2bf(v);
    }
    __syncthreads();

    const int wave = tid >> 6, l = tid & 63;
    const int wm = wave >> 1, wn = wave & 1;
    const int g  = l >> 5,  ln = l & 31;
    const int g16 = g * 16;   // byte offset of this lane-group's 8 channels

    int py[2], px[2];
    #pragma unroll
    for (int ntp = 0; ntp < 2; ++ntp) {
        int p = wn * 64 + ntp * 32 + ln;   // pixel index in 8x16 tile
        py[ntp] = p >> 4;
        px[ntp] = p & 15;
    }

    f32x16 acc[2][2];
    #pragma unroll
    for (int i = 0; i < 2; ++i)
        #pragma unroll
        for (int j = 0; j < 2; ++j)
            #pragma unroll
            for (int q = 0; q < 16; ++q) acc[i][j][q] = 0.0f;

    const uint4* __restrict__ pwv = (const uint4*)pw;

    #pragma unroll 1
    for (int ij = 0; ij < 9; ++ij) {
        const int di = ij / 3;
        const int dj = ij - di * 3;
        unsigned int bbase[2], sw[2];
        #pragma unroll
        for (int ntp = 0; ntp < 2; ++ntp) {
            int yy = py[ntp] + di, xx = px[ntp] + dj;
            bbase[ntp] = (unsigned int)((yy * HALO_X + xx) * (C_IN * 2) + g16);
            sw[ntp]    = (unsigned int)((xx & 7) << 4);
        }
        #pragma unroll
        for (int cs = 0; cs < 4; ++cs) {
            const int t = ij * 4 + cs;
            bf16x8 a0 = __builtin_bit_cast(bf16x8, pwv[(t * 4 + wm * 2 + 0) * 64 + l]);
            bf16x8 a1 = __builtin_bit_cast(bf16x8, pwv[(t * 4 + wm * 2 + 1) * 64 + l]);
            // swizzle XOR applied AFTER adding the channel offset (cs*32 bytes)
            bf16x8 b0 = __builtin_bit_cast(bf16x8,
                *(const uint4*)((const char*)xs + ((bbase[0] + cs * 32) ^ sw[0])));
            bf16x8 b1 = __builtin_bit_cast(bf16x8,
                *(const uint4*)((const char*)xs + ((bbase[1] + cs * 32) ^ sw[1])));
            acc[0][0] = __builtin_amdgcn_mfma_f32_32x32x16_bf16(a0, b0, acc[0][0], 0, 0, 0);
            acc[0][1] = __builtin_amdgcn_mfma_f32_32x32x16_bf16(a0, b1, acc[0][1], 0, 0, 0);
            acc[1][0] = __builtin_amdgcn_mfma_f32_32x32x16_bf16(a1, b0, acc[1][0], 0, 0, 0);
            acc[1][1] = __builtin_amdgcn_mfma_f32_32x32x16_bf16(a1, b1, acc[1][1], 0, 0, 0);
        }
    }

    // ---- epilogue: C/D layout col=lane&31 (pixel), row=(r&3)+8*(r>>2)+4*(lane>>5) ----
    const size_t outb = (size_t)b * C_OUT * HH * WW;
    #pragma unroll
    for (int mtp = 0; mtp < 2; ++mtp) {
        #pragma unroll
        for (int r = 0; r < 16; ++r) {
            int mloc = (r & 3) + 8 * (r >> 2) + 4 * g;
            int o = (wm * 2 + mtp) * 32 + mloc;
            float bv = bias[o];
            #pragma unroll
            for (int ntp = 0; ntp < 2; ++ntp) {
                int p  = wn * 64 + ntp * 32 + ln;
                int gh = h0 + (p >> 4), gw = w0 + (p & 15);
                out[outb + ((size_t)o * HH + gh) * WW + gw] = acc[mtp][ntp][r] + bv;
            }
        }
    }
}

extern "C" void kernel_launch(void* const* d_in, const int* in_sizes, int n_in,
                              void* d_out, int out_size, void* d_ws, size_t ws_size,
                              hipStream_t stream) {
    const float* x    = (const float*)d_in[0];
    const float* w    = (const float*)d_in[1];
    const float* mk   = (const float*)d_in[2];
    const float* bs   = (const float*)d_in[3];
    float* out        = (float*)d_out;
    unsigned short* pw = (unsigned short*)d_ws;   // 144 KiB used

    pack_w_kernel<<<dim3(NSTEPS), dim3(256), 0, stream>>>(w, mk, pw);
    sparse_conv_kernel<<<dim3(NB * TILES_X * TILES_Y), dim3(256), 0, stream>>>(x, pw, bs, out);
}

// Round 2
// 88.213 us; speedup vs baseline: 1.7367x; 1.7367x over previous
//
#include <hip/hip_runtime.h>
#include <hip/hip_bf16.h>

#define C_IN    64
#define C_OUT   128
#define HH      112
#define WW      112
#define NB      16
#define KTOT    576      // C_IN * 9
#define TY      8
#define TX      16
#define HALO_Y  10
#define HALO_X  18
#define HALO_P  (HALO_Y*HALO_X)        // 180 halo pixels
#define NSTEPS  36       // KTOT / 16
#define TILES_X 7
#define TILES_Y 14

typedef __bf16 bf16x8 __attribute__((ext_vector_type(8)));
typedef float  f32x16 __attribute__((ext_vector_type(16)));

static __device__ __forceinline__ unsigned short f2bf(float v) {
    unsigned int u = __builtin_bit_cast(unsigned int, v);
    u = u + 0x7fffu + ((u >> 16) & 1u);   // RNE
    return (unsigned short)(u >> 16);
}

// Pack spW = weight*mask into bf16 MFMA A-fragments, K reordered to (i,j,c).
// pw_frag[t][mt][lane] = 16 bytes (8 bf16), t=K-step (0..35), mt=M-tile (0..3).
// k_log(t, g=lane>>5, e) = t*16 + g*8 + e ;  ij = k_log>>6, c = k_log&63 ; k_orig = c*9 + ij
__global__ __launch_bounds__(256) void pack_w_kernel(
        const float* __restrict__ weight, const float* __restrict__ mask,
        unsigned short* __restrict__ pw) {
    int t  = blockIdx.x;           // 0..35
    int mt = threadIdx.x >> 6;     // 0..3
    int l  = threadIdx.x & 63;
    int g  = l >> 5;
    int m  = mt * 32 + (l & 31);
    unsigned int words[4];
    #pragma unroll
    for (int ew = 0; ew < 4; ++ew) {
        unsigned int w2[2];
        #pragma unroll
        for (int h = 0; h < 2; ++h) {
            int e    = ew * 2 + h;
            int klog = t * 16 + g * 8 + e;
            int ij   = klog >> 6;
            int c    = klog & 63;
            int ko   = c * 9 + ij;
            w2[h] = f2bf(weight[m * KTOT + ko] * mask[m * KTOT + ko]);
        }
        words[ew] = w2[0] | (w2[1] << 16);
    }
    uint4 o4; o4.x = words[0]; o4.y = words[1]; o4.z = words[2]; o4.w = words[3];
    ((uint4*)pw)[(t * 4 + mt) * 64 + l] = o4;
}

// Implicit-GEMM conv. Block = one batch, one 8x16 spatial tile, all 128 c_out.
// LDS layout: [halo_pixel P][channel] bf16, with 16B-slot swizzle slot=(cblk^P)&7.
__global__ __launch_bounds__(256, 4) void sparse_conv_kernel(
        const float* __restrict__ x, const unsigned short* __restrict__ pw,
        const float* __restrict__ bias, float* __restrict__ out) {
    __shared__ __align__(16) unsigned short xs[HALO_P * C_IN];   // 23040 B

    const int bid = blockIdx.x;
    const int b   = bid / (TILES_X * TILES_Y);
    const int t98 = bid % (TILES_X * TILES_Y);
    const int tyi = t98 / TILES_X;
    const int txi = t98 % TILES_X;
    const int h0  = tyi * TY, w0 = txi * TX;
    const int tid = threadIdx.x;

    // ---- stage halo: thread p owns halo pixel p; 64 independent loads, 8 b128 writes ----
    const float* xb = x + (size_t)b * C_IN * HH * WW;
    {
        const int p  = tid;
        const bool act = p < HALO_P;
        int yy = p / HALO_X;
        int xx = p - yy * HALO_X;
        int gh = h0 + yy - 1, gw = w0 + xx - 1;
        const bool valid = act && (unsigned)gh < (unsigned)HH && (unsigned)gw < (unsigned)WW;
        const float* bp = xb + (gh * WW + gw);
        float v[C_IN];
        #pragma unroll
        for (int c = 0; c < C_IN; ++c)
            v[c] = valid ? bp[c * (HH * WW)] : 0.0f;
        if (act) {
            char* xc = (char*)xs + p * (C_IN * 2);
            #pragma unroll
            for (int j = 0; j < 8; ++j) {
                bf16x8 bv;
                #pragma unroll
                for (int e = 0; e < 8; ++e) bv[e] = (__bf16)v[j * 8 + e];
                *(uint4*)(xc + (((j ^ p) & 7) << 4)) = __builtin_bit_cast(uint4, bv);
            }
        }
    }
    __syncthreads();

    const int wave = tid >> 6, l = tid & 63;
    const int wm = wave >> 1, wn = wave & 1;
    const int g  = l >> 5,  ln = l & 31;

    int P0[2];
    #pragma unroll
    for (int ntp = 0; ntp < 2; ++ntp) {
        int pt = wn * 64 + ntp * 32 + ln;   // pixel index in 8x16 tile
        P0[ntp] = (pt >> 4) * HALO_X + (pt & 15);
    }

    f32x16 acc[2][2];
    #pragma unroll
    for (int i = 0; i < 2; ++i)
        #pragma unroll
        for (int j = 0; j < 2; ++j)
            #pragma unroll
            for (int q = 0; q < 16; ++q) acc[i][j][q] = 0.0f;

    const uint4* __restrict__ pwv = (const uint4*)pw;

    #pragma unroll 1
    for (int ij = 0; ij < 9; ++ij) {
        const int di = ij / 3;
        const int dj = ij - di * 3;
        const int P0a = P0[0] + di * HALO_X + dj;
        const int P1a = P0[1] + di * HALO_X + dj;
        #pragma unroll
        for (int cs = 0; cs < 4; ++cs) {
            const int t = ij * 4 + cs;
            bf16x8 a0 = __builtin_bit_cast(bf16x8, pwv[(t * 4 + wm * 2 + 0) * 64 + l]);
            bf16x8 a1 = __builtin_bit_cast(bf16x8, pwv[(t * 4 + wm * 2 + 1) * 64 + l]);
            const int jb = cs * 2 + g;   // 16B channel-block index
            bf16x8 b0 = __builtin_bit_cast(bf16x8,
                *(const uint4*)((const char*)xs + P0a * (C_IN * 2) + (((jb ^ P0a) & 7) << 4)));
            bf16x8 b1 = __builtin_bit_cast(bf16x8,
                *(const uint4*)((const char*)xs + P1a * (C_IN * 2) + (((jb ^ P1a) & 7) << 4)));
            acc[0][0] = __builtin_amdgcn_mfma_f32_32x32x16_bf16(a0, b0, acc[0][0], 0, 0, 0);
            acc[0][1] = __builtin_amdgcn_mfma_f32_32x32x16_bf16(a0, b1, acc[0][1], 0, 0, 0);
            acc[1][0] = __builtin_amdgcn_mfma_f32_32x32x16_bf16(a1, b0, acc[1][0], 0, 0, 0);
            acc[1][1] = __builtin_amdgcn_mfma_f32_32x32x16_bf16(a1, b1, acc[1][1], 0, 0, 0);
        }
    }

    // ---- epilogue: C/D layout col=lane&31 (pixel), row=(r&3)+8*(r>>2)+4*(lane>>5) ----
    const size_t outb = (size_t)b * C_OUT * HH * WW;
    #pragma unroll
    for (int mtp = 0; mtp < 2; ++mtp) {
        #pragma unroll
        for (int r = 0; r < 16; ++r) {
            int mloc = (r & 3) + 8 * (r >> 2) + 4 * g;
            int o = (wm * 2 + mtp) * 32 + mloc;
            float bv = bias[o];
            #pragma unroll
            for (int ntp = 0; ntp < 2; ++ntp) {
                int p  = wn * 64 + ntp * 32 + ln;
                int gh = h0 + (p >> 4), gw = w0 + (p & 15);
                out[outb + ((size_t)o * HH + gh) * WW + gw] = acc[mtp][ntp][r] + bv;
            }
        }
    }
}

extern "C" void kernel_launch(void* const* d_in, const int* in_sizes, int n_in,
                              void* d_out, int out_size, void* d_ws, size_t ws_size,
                              hipStream_t stream) {
    const float* x    = (const float*)d_in[0];
    const float* w    = (const float*)d_in[1];
    const float* mk   = (const float*)d_in[2];
    const float* bs   = (const float*)d_in[3];
    float* out        = (float*)d_out;
    unsigned short* pw = (unsigned short*)d_ws;   // 144 KiB used

    pack_w_kernel<<<dim3(NSTEPS), dim3(256), 0, stream>>>(w, mk, pw);
    sparse_conv_kernel<<<dim3(NB * TILES_X * TILES_Y), dim3(256), 0, stream>>>(x, pw, bs, out);
}

// Round 3
// 83.332 us; speedup vs baseline: 1.8384x; 1.0586x over previous
//
#include <hip/hip_runtime.h>
#include <hip/hip_bf16.h>

#define C_IN    64
#define C_OUT   128
#define HH      112
#define WW      112
#define NB      16
#define KTOT    576      // C_IN * 9
#define TY      8
#define TX      16
#define HALO_Y  10
#define HALO_X  18
#define HALO_P  (HALO_Y*HALO_X)        // 180 halo pixels
#define NSTEPS  36       // KTOT / 16
#define TILES_X 7
#define TILES_Y 14
#define NTILES  (TILES_X*TILES_Y)      // 98
#define PH      114                    // padded spatial dim
#define PPIX    (PH*PH)                // 12996 padded pixels
#define XT_OFF  147456                 // bytes: pw occupies [0, 147456)
#define XT_BYTES ((size_t)NB * PPIX * C_IN * 2)

typedef __bf16 bf16x8 __attribute__((ext_vector_type(8)));
typedef float  f32x16 __attribute__((ext_vector_type(16)));

static __device__ __forceinline__ unsigned short f2bf(float v) {
    unsigned int u = __builtin_bit_cast(unsigned int, v);
    u = u + 0x7fffu + ((u >> 16) & 1u);   // RNE
    return (unsigned short)(u >> 16);
}

// ---------------- pack spW = weight*mask into bf16 MFMA A-fragments ----------------
// pw_frag[t][mt][lane] = 16 B (8 bf16); k_log(t,g,e)=t*16+g*8+e; ij=k_log>>6, c=k_log&63; k_orig=c*9+ij
__global__ __launch_bounds__(256) void pack_w_kernel(
        const float* __restrict__ weight, const float* __restrict__ mask,
        unsigned short* __restrict__ pw) {
    int t  = blockIdx.x;           // 0..35
    int mt = threadIdx.x >> 6;     // 0..3
    int l  = threadIdx.x & 63;
    int g  = l >> 5;
    int m  = mt * 32 + (l & 31);
    unsigned int words[4];
    #pragma unroll
    for (int ew = 0; ew < 4; ++ew) {
        unsigned int w2[2];
        #pragma unroll
        for (int h = 0; h < 2; ++h) {
            int e    = ew * 2 + h;
            int klog = t * 16 + g * 8 + e;
            int ij   = klog >> 6;
            int c    = klog & 63;
            int ko   = c * 9 + ij;
            w2[h] = f2bf(weight[m * KTOT + ko] * mask[m * KTOT + ko]);
        }
        words[ew] = w2[0] | (w2[1] << 16);
    }
    uint4 o4; o4.x = words[0]; o4.y = words[1]; o4.z = words[2]; o4.w = words[3];
    ((uint4*)pw)[(t * 4 + mt) * 64 + l] = o4;
}

// ---------------- pre-pass: x [b][c][h][w] fp32 -> xT [b][hp][wp][c] bf16, zero-padded ----------------
__global__ __launch_bounds__(256) void transpose_x_kernel(
        const float* __restrict__ x, unsigned short* __restrict__ xT) {
    const int b  = blockIdx.y;
    const int pp = blockIdx.x * 256 + threadIdx.x;
    if (pp >= PPIX) return;
    const int hp = pp / PH, wp = pp - hp * PH;
    const int gh = hp - 1, gw = wp - 1;
    const bool valid = (unsigned)gh < (unsigned)HH && (unsigned)gw < (unsigned)WW;
    const float* src = x + (size_t)b * C_IN * (HH * WW) + (gh * WW + gw);
    uint4* dst = (uint4*)(xT + ((size_t)b * PPIX + pp) * C_IN);
    #pragma unroll
    for (int cb = 0; cb < 8; ++cb) {
        unsigned int w4[4];
        #pragma unroll
        for (int h = 0; h < 4; ++h) {
            float v0 = valid ? src[(size_t)(cb * 8 + h * 2    ) * (HH * WW)] : 0.0f;
            float v1 = valid ? src[(size_t)(cb * 8 + h * 2 + 1) * (HH * WW)] : 0.0f;
            w4[h] = (unsigned)f2bf(v0) | ((unsigned)f2bf(v1) << 16);
        }
        uint4 o; o.x = w4[0]; o.y = w4[1]; o.z = w4[2]; o.w = w4[3];
        dst[cb] = o;
    }
}

// ---------------- main conv: staging via global_load_lds from xT (pre-swizzled source) ----------------
__global__ __launch_bounds__(256, 4) void sparse_conv_xt_kernel(
        const unsigned short* __restrict__ xT, const unsigned short* __restrict__ pw,
        const float* __restrict__ bias, float* __restrict__ out) {
    __shared__ __align__(16) unsigned short xs[1536 * 8];   // 24576 B (23040 used + clamp slack)

    // XCD-bijective swizzle: 1568 % 8 == 0; XCD k gets 196 contiguous logical tiles (2 images)
    const int bid = (blockIdx.x & 7) * (NB * NTILES / 8) + (blockIdx.x >> 3);
    const int b   = bid / NTILES;
    const int t98 = bid % NTILES;
    const int tyi = t98 / TILES_X;
    const int txi = t98 % TILES_X;
    const int h0  = tyi * TY, w0 = txi * TX;
    const int tid = threadIdx.x;
    const int wave = tid >> 6, l = tid & 63;

    // ---- stage halo: 6 rounds of global_load_lds dwordx4, linear LDS dest, swizzled source ----
    {
        const char* xTb = (const char*)xT + (size_t)b * PPIX * (C_IN * 2);
        #pragma unroll
        for (int r = 0; r < 6; ++r) {
            int chunk = r * 256 + tid;          // 16B chunk index = p*8 + slot
            int p = chunk >> 3; if (p > HALO_P - 1) p = HALO_P - 1;   // clamp tail
            int s = chunk & 7;
            int yy = p / HALO_X, xx = p - yy * HALO_X;
            int hp = h0 + yy, wp = w0 + xx;     // padded coords (halo -1 absorbed by pad)
            const char* g = xTb + (size_t)(hp * PH + wp) * (C_IN * 2) + (((s ^ p) & 7) << 4);
            char* lp = (char*)xs + r * 4096 + wave * 1024;   // + lane*16 done by HW
            __builtin_amdgcn_global_load_lds(
                (const __attribute__((address_space(1))) void*)g,
                (__attribute__((address_space(3))) void*)lp, 16, 0, 0);
        }
    }
    __syncthreads();

    const int wm = wave >> 1, wn = wave & 1;
    const int g  = l >> 5,  ln = l & 31;

    int P0[2];
    #pragma unroll
    for (int ntp = 0; ntp < 2; ++ntp) {
        int pt = wn * 64 + ntp * 32 + ln;   // pixel index in 8x16 tile
        P0[ntp] = (pt >> 4) * HALO_X + (pt & 15);
    }

    f32x16 acc[2][2];
    #pragma unroll
    for (int i = 0; i < 2; ++i)
        #pragma unroll
        for (int j = 0; j < 2; ++j)
            #pragma unroll
            for (int q = 0; q < 16; ++q) acc[i][j][q] = 0.0f;

    const uint4* __restrict__ pwv = (const uint4*)pw;

    #pragma unroll 1
    for (int ij = 0; ij < 9; ++ij) {
        const int di = ij / 3;
        const int dj = ij - di * 3;
        const int P0a = P0[0] + di * HALO_X + dj;
        const int P1a = P0[1] + di * HALO_X + dj;
        #pragma unroll
        for (int cs = 0; cs < 4; ++cs) {
            const int t = ij * 4 + cs;
            bf16x8 a0 = __builtin_bit_cast(bf16x8, pwv[(t * 4 + wm * 2 + 0) * 64 + l]);
            bf16x8 a1 = __builtin_bit_cast(bf16x8, pwv[(t * 4 + wm * 2 + 1) * 64 + l]);
            const int jb = cs * 2 + g;   // 16B channel-block index
            bf16x8 b0 = __builtin_bit_cast(bf16x8,
                *(const uint4*)((const char*)xs + P0a * (C_IN * 2) + (((jb ^ P0a) & 7) << 4)));
            bf16x8 b1 = __builtin_bit_cast(bf16x8,
                *(const uint4*)((const char*)xs + P1a * (C_IN * 2) + (((jb ^ P1a) & 7) << 4)));
            acc[0][0] = __builtin_amdgcn_mfma_f32_32x32x16_bf16(a0, b0, acc[0][0], 0, 0, 0);
            acc[0][1] = __builtin_amdgcn_mfma_f32_32x32x16_bf16(a0, b1, acc[0][1], 0, 0, 0);
            acc[1][0] = __builtin_amdgcn_mfma_f32_32x32x16_bf16(a1, b0, acc[1][0], 0, 0, 0);
            acc[1][1] = __builtin_amdgcn_mfma_f32_32x32x16_bf16(a1, b1, acc[1][1], 0, 0, 0);
        }
    }

    // ---- epilogue: C/D layout col=lane&31 (pixel), row=(r&3)+8*(r>>2)+4*(lane>>5) ----
    const size_t outb = (size_t)b * C_OUT * HH * WW;
    #pragma unroll
    for (int mtp = 0; mtp < 2; ++mtp) {
        #pragma unroll
        for (int r = 0; r < 16; ++r) {
            int mloc = (r & 3) + 8 * (r >> 2) + 4 * g;
            int o = (wm * 2 + mtp) * 32 + mloc;
            float bv = bias[o];
            #pragma unroll
            for (int ntp = 0; ntp < 2; ++ntp) {
                int p  = wn * 64 + ntp * 32 + ln;
                int gh = h0 + (p >> 4), gw = w0 + (p & 15);
                out[outb + ((size_t)o * HH + gh) * WW + gw] = acc[mtp][ntp][r] + bv;
            }
        }
    }
}

// ---------------- fallback (round-2 kernel) if ws too small for xT ----------------
__global__ __launch_bounds__(256, 4) void sparse_conv_fb_kernel(
        const float* __restrict__ x, const unsigned short* __restrict__ pw,
        const float* __restrict__ bias, float* __restrict__ out) {
    __shared__ __align__(16) unsigned short xs[HALO_P * C_IN];

    const int bid = blockIdx.x;
    const int b   = bid / NTILES;
    const int t98 = bid % NTILES;
    const int tyi = t98 / TILES_X;
    const int txi = t98 % TILES_X;
    const int h0  = tyi * TY, w0 = txi * TX;
    const int tid = threadIdx.x;

    const float* xb = x + (size_t)b * C_IN * HH * WW;
    {
        const int p  = tid;
        const bool act = p < HALO_P;
        int yy = p / HALO_X;
        int xx = p - yy * HALO_X;
        int gh = h0 + yy - 1, gw = w0 + xx - 1;
        const bool valid = act && (unsigned)gh < (unsigned)HH && (unsigned)gw < (unsigned)WW;
        const float* bp = xb + (gh * WW + gw);
        float v[C_IN];
        #pragma unroll
        for (int c = 0; c < C_IN; ++c)
            v[c] = valid ? bp[c * (HH * WW)] : 0.0f;
        if (act) {
            char* xc = (char*)xs + p * (C_IN * 2);
            #pragma unroll
            for (int j = 0; j < 8; ++j) {
                bf16x8 bv;
                #pragma unroll
                for (int e = 0; e < 8; ++e) bv[e] = (__bf16)v[j * 8 + e];
                *(uint4*)(xc + (((j ^ p) & 7) << 4)) = __builtin_bit_cast(uint4, bv);
            }
        }
    }
    __syncthreads();

    const int wave = tid >> 6, l = tid & 63;
    const int wm = wave >> 1, wn = wave & 1;
    const int g  = l >> 5,  ln = l & 31;

    int P0[2];
    #pragma unroll
    for (int ntp = 0; ntp < 2; ++ntp) {
        int pt = wn * 64 + ntp * 32 + ln;
        P0[ntp] = (pt >> 4) * HALO_X + (pt & 15);
    }

    f32x16 acc[2][2];
    #pragma unroll
    for (int i = 0; i < 2; ++i)
        #pragma unroll
        for (int j = 0; j < 2; ++j)
            #pragma unroll
            for (int q = 0; q < 16; ++q) acc[i][j][q] = 0.0f;

    const uint4* __restrict__ pwv = (const uint4*)pw;

    #pragma unroll 1
    for (int ij = 0; ij < 9; ++ij) {
        const int di = ij / 3;
        const int dj = ij - di * 3;
        const int P0a = P0[0] + di * HALO_X + dj;
        const int P1a = P0[1] + di * HALO_X + dj;
        #pragma unroll
        for (int cs = 0; cs < 4; ++cs) {
            const int t = ij * 4 + cs;
            bf16x8 a0 = __builtin_bit_cast(bf16x8, pwv[(t * 4 + wm * 2 + 0) * 64 + l]);
            bf16x8 a1 = __builtin_bit_cast(bf16x8, pwv[(t * 4 + wm * 2 + 1) * 64 + l]);
            const int jb = cs * 2 + g;
            bf16x8 b0 = __builtin_bit_cast(bf16x8,
                *(const uint4*)((const char*)xs + P0a * (C_IN * 2) + (((jb ^ P0a) & 7) << 4)));
            bf16x8 b1 = __builtin_bit_cast(bf16x8,
                *(const uint4*)((const char*)xs + P1a * (C_IN * 2) + (((jb ^ P1a) & 7) << 4)));
            acc[0][0] = __builtin_amdgcn_mfma_f32_32x32x16_bf16(a0, b0, acc[0][0], 0, 0, 0);
            acc[0][1] = __builtin_amdgcn_mfma_f32_32x32x16_bf16(a0, b1, acc[0][1], 0, 0, 0);
            acc[1][0] = __builtin_amdgcn_mfma_f32_32x32x16_bf16(a1, b0, acc[1][0], 0, 0, 0);
            acc[1][1] = __builtin_amdgcn_mfma_f32_32x32x16_bf16(a1, b1, acc[1][1], 0, 0, 0);
        }
    }

    const size_t outb = (size_t)b * C_OUT * HH * WW;
    #pragma unroll
    for (int mtp = 0; mtp < 2; ++mtp) {
        #pragma unroll
        for (int r = 0; r < 16; ++r) {
            int mloc = (r & 3) + 8 * (r >> 2) + 4 * g;
            int o = (wm * 2 + mtp) * 32 + mloc;
            float bv = bias[o];
            #pragma unroll
            for (int ntp = 0; ntp < 2; ++ntp) {
                int p  = wn * 64 + ntp * 32 + ln;
                int gh = h0 + (p >> 4), gw = w0 + (p & 15);
                out[outb + ((size_t)o * HH + gh) * WW + gw] = acc[mtp][ntp][r] + bv;
            }
        }
    }
}

extern "C" void kernel_launch(void* const* d_in, const int* in_sizes, int n_in,
                              void* d_out, int out_size, void* d_ws, size_t ws_size,
                              hipStream_t stream) {
    const float* x    = (const float*)d_in[0];
    const float* w    = (const float*)d_in[1];
    const float* mk   = (const float*)d_in[2];
    const float* bs   = (const float*)d_in[3];
    float* out        = (float*)d_out;
    unsigned short* pw = (unsigned short*)d_ws;   // [0, 147456)

    pack_w_kernel<<<dim3(NSTEPS), dim3(256), 0, stream>>>(w, mk, pw);

    if (ws_size >= (size_t)XT_OFF + XT_BYTES) {
        unsigned short* xT = (unsigned short*)((char*)d_ws + XT_OFF);
        transpose_x_kernel<<<dim3((PPIX + 255) / 256, NB), dim3(256), 0, stream>>>(x, xT);
        sparse_conv_xt_kernel<<<dim3(NB * NTILES), dim3(256), 0, stream>>>(xT, pw, bs, out);
    } else {
        sparse_conv_fb_kernel<<<dim3(NB * NTILES), dim3(256), 0, stream>>>(x, pw, bs, out);
    }
}